// Round 1
// baseline (3039.840 us; speedup 1.0000x reference)
//
#include <hip/hip_runtime.h>
#include <math.h>

// Problem constants (B=16, T=64, NN=4096, H=1024)
constexpr int kB = 16;
constexpr int kT = 64;
constexpr int kH = 1024;

// ---------------------------------------------------------------------------
// Tiled fp32 GEMM, "NT" form with bias:  C[M,N] = X[M,K] @ W[N,K]^T + bias[N]
// Block tile 64x64, K-tile 16, 256 threads, 4x4 micro-tile per thread.
// N and K must be multiples of 64/16 (true for all three uses); M is guarded.
// ---------------------------------------------------------------------------
#define GBM 64
#define GBN 64
#define GBK 16

__global__ __launch_bounds__(256)
void gemm_nt_bias(const float* __restrict__ X,   // [M,K]
                  const float* __restrict__ W,   // [N,K]
                  const float* __restrict__ bias,// [N]
                  float* __restrict__ C,         // [M,N]
                  int M, int N, int K)
{
    __shared__ float Xs[GBK][GBM + 1];
    __shared__ float Ws[GBK][GBN + 1];

    const int tid = threadIdx.x;          // 0..255
    const int bm = blockIdx.y * GBM;
    const int bn = blockIdx.x * GBN;
    const int tm = (tid >> 4) * 4;        // 0..60
    const int tn = (tid & 15) * 4;        // 0..60

    // loader mapping: each thread loads one float4 of each tile
    const int lr = tid >> 2;              // row within tile 0..63
    const int lc = (tid & 3) * 4;         // k within tile {0,4,8,12}

    float acc[4][4] = {};

    for (int k0 = 0; k0 < K; k0 += GBK) {
        // X tile (guarded rows)
        {
            const int gr = bm + lr;
            float4 v = make_float4(0.f, 0.f, 0.f, 0.f);
            if (gr < M) v = *(const float4*)(X + (long)gr * K + k0 + lc);
            Xs[lc + 0][lr] = v.x; Xs[lc + 1][lr] = v.y;
            Xs[lc + 2][lr] = v.z; Xs[lc + 3][lr] = v.w;
        }
        // W tile (always in bounds: N % 64 == 0, K % 16 == 0)
        {
            const int gr = bn + lr;
            const float4 v = *(const float4*)(W + (long)gr * K + k0 + lc);
            Ws[lc + 0][lr] = v.x; Ws[lc + 1][lr] = v.y;
            Ws[lc + 2][lr] = v.z; Ws[lc + 3][lr] = v.w;
        }
        __syncthreads();

        #pragma unroll
        for (int k = 0; k < GBK; ++k) {
            const float a0 = Xs[k][tm + 0], a1 = Xs[k][tm + 1];
            const float a2 = Xs[k][tm + 2], a3 = Xs[k][tm + 3];
            const float b0 = Ws[k][tn + 0], b1 = Ws[k][tn + 1];
            const float b2 = Ws[k][tn + 2], b3 = Ws[k][tn + 3];
            acc[0][0] += a0 * b0; acc[0][1] += a0 * b1; acc[0][2] += a0 * b2; acc[0][3] += a0 * b3;
            acc[1][0] += a1 * b0; acc[1][1] += a1 * b1; acc[1][2] += a1 * b2; acc[1][3] += a1 * b3;
            acc[2][0] += a2 * b0; acc[2][1] += a2 * b1; acc[2][2] += a2 * b2; acc[2][3] += a2 * b3;
            acc[3][0] += a3 * b0; acc[3][1] += a3 * b1; acc[3][2] += a3 * b2; acc[3][3] += a3 * b3;
        }
        __syncthreads();
    }

    #pragma unroll
    for (int i = 0; i < 4; ++i) {
        const int gr = bm + tm + i;
        if (gr >= M) continue;
        #pragma unroll
        for (int jj = 0; jj < 4; ++jj) {
            const int gc = bn + tn + jj;
            C[(long)gr * N + gc] = acc[i][jj] + bias[gc];
        }
    }
}

// ---------------------------------------------------------------------------
// One GRU timestep (fused gh-matvec + cell update), PyTorch gate order r,z,n.
//   gh[b, g*H+j] = h_prev[b,:] . w_hh[g*H+j,:] + b_hh[g*H+j]
//   r = sig(xr+hr); z = sig(xz+hz); n = tanh(xn + r*hn)
//   h_new = (1-z)*n + z*h_prev
// Grid: 256 blocks x 192 threads. Block owns 4 j-columns; thread = (b, jl, g)
// computing one full 1024-length dot. h_prev staged in LDS in two 512-chunks
// (pad=4 floats keeps float4 alignment and only 2-way bank aliasing = free).
// Weights are partitioned across blocks -> w_hh read exactly once per step.
// ---------------------------------------------------------------------------
__global__ __launch_bounds__(192)
void gru_step(const float* __restrict__ gx_t,  // gates_x base at timestep t
              long gx_bstride,                 // elements between batches (T*3H)
              const float* __restrict__ w_hh,  // [3H, H]
              const float* __restrict__ b_hh,  // [3H]
              const float* __restrict__ h_prev,// h_{t-1} base (dummy if zero_init)
              long hp_bstride,                 // elements between batches
              int zero_init,
              float* __restrict__ h_out,       // h_t base
              long ho_bstride)
{
    __shared__ float hs[kB][516];    // 512 + pad 4
    __shared__ float gh_s[3][64];

    const int tid = threadIdx.x;     // 0..191
    const int b  = tid & 15;
    const int jl = (tid >> 4) & 3;
    const int g  = tid / 64;         // 0..2 (gate)
    const int j  = blockIdx.x * 4 + jl;

    const float* wrow = w_hh + (long)(g * kH + j) * kH;
    float d = 0.f;

    for (int kt = 0; kt < 2; ++kt) {
        const int k0 = kt * 512;
        __syncthreads();   // protect hs from previous chunk's readers
        // cooperative load of h_prev[:, k0:k0+512] -> 2048 float4 / 192 threads
        for (int idx = tid; idx < 2048; idx += 192) {
            const int bb = idx >> 7;            // 0..15
            const int kk = (idx & 127) * 4;     // 0..508
            float4 v = make_float4(0.f, 0.f, 0.f, 0.f);
            if (!zero_init)
                v = *(const float4*)(h_prev + (long)bb * hp_bstride + k0 + kk);
            *(float4*)&hs[bb][kk] = v;
        }
        __syncthreads();

        #pragma unroll 8
        for (int k = 0; k < 512; k += 4) {
            const float4 w4 = *(const float4*)(wrow + k0 + k);
            const float4 h4 = *(const float4*)&hs[b][k];
            d += w4.x * h4.x + w4.y * h4.y + w4.z * h4.z + w4.w * h4.w;
        }
    }

    d += b_hh[g * kH + j];
    gh_s[g][jl * 16 + b] = d;
    __syncthreads();

    if (tid < 64) {
        const int pb = tid & 15;
        const int pj = tid >> 4;             // 0..3
        const int jg = blockIdx.x * 4 + pj;
        const float* gxrow = gx_t + (long)pb * gx_bstride;
        const float xr = gxrow[jg];
        const float xz = gxrow[kH + jg];
        const float xn = gxrow[2 * kH + jg];
        const float hr = gh_s[0][pj * 16 + pb];
        const float hz = gh_s[1][pj * 16 + pb];
        const float hn = gh_s[2][pj * 16 + pb];
        const float hp = zero_init ? 0.f : h_prev[(long)pb * hp_bstride + jg];
        const float r = 1.f / (1.f + __expf(-(xr + hr)));
        const float z = 1.f / (1.f + __expf(-(xz + hz)));
        const float n = tanhf(xn + r * hn);
        h_out[(long)pb * ho_bstride + jg] = (1.f - z) * n + z * hp;
    }
}

// ---------------------------------------------------------------------------
// kernel_launch
// ---------------------------------------------------------------------------
extern "C" void kernel_launch(void* const* d_in, const int* in_sizes, int n_in,
                              void* d_out, int out_size, void* d_ws, size_t ws_size,
                              hipStream_t stream)
{
    const float* x        = (const float*)d_in[0];   // [16,64,4096]
    const float* w_ih_l0  = (const float*)d_in[1];   // [3072,4096]
    const float* w_hh_l0  = (const float*)d_in[2];   // [3072,1024]
    const float* b_ih_l0  = (const float*)d_in[3];   // [3072]
    const float* b_hh_l0  = (const float*)d_in[4];   // [3072]
    const float* w_ih_l1  = (const float*)d_in[5];   // [3072,1024]
    const float* w_hh_l1  = (const float*)d_in[6];   // [3072,1024]
    const float* b_ih_l1  = (const float*)d_in[7];   // [3072]
    const float* b_hh_l1  = (const float*)d_in[8];   // [3072]
    const float* dec_w    = (const float*)d_in[9];   // [4096,1024]
    const float* dec_b    = (const float*)d_in[10];  // [4096]
    float* out = (float*)d_out;                      // [16,4096]

    // Workspace layout (floats). gx1 reuses gx0's buffer (dead after layer 0).
    float* ws   = (float*)d_ws;
    float* gx0  = ws;                                   // [1024, 3072] rows (b*T+t)
    float* h1   = gx0 + (size_t)1024 * 3072;            // [1024, 1024] rows (b*T+t)
    float* bufA = h1 + (size_t)1024 * 1024;             // [16, 1024]
    float* bufB = bufA + (size_t)kB * kH;               // [16, 1024]
    float* gx1  = gx0;                                  // alias (sequential reuse)

    const long gx_bstride = (long)kT * 3 * kH;          // 196608
    const long h1_bstride = (long)kT * kH;              // 65536

    // Phase A: gx0 = x @ w_ih_l0^T + b_ih_l0   (M=1024, N=3072, K=4096)
    gemm_nt_bias<<<dim3(3072 / GBN, 1024 / GBM), 256, 0, stream>>>(
        x, w_ih_l0, b_ih_l0, gx0, 1024, 3072, 4096);

    // Layer 0 recurrence: h1 rows (b*T+t)
    for (int t = 0; t < kT; ++t) {
        const float* hp = (t == 0) ? h1 : (h1 + (size_t)(t - 1) * kH);
        gru_step<<<256, 192, 0, stream>>>(
            gx0 + (size_t)t * 3 * kH, gx_bstride,
            w_hh_l0, b_hh_l0,
            hp, h1_bstride, (t == 0) ? 1 : 0,
            h1 + (size_t)t * kH, h1_bstride);
    }

    // Phase C: gx1 = h1 @ w_ih_l1^T + b_ih_l1   (M=1024, N=3072, K=1024)
    gemm_nt_bias<<<dim3(3072 / GBN, 1024 / GBM), 256, 0, stream>>>(
        h1, w_ih_l1, b_ih_l1, gx1, 1024, 3072, 1024);

    // Layer 1 recurrence: ping-pong 16x1024 buffers; t=63 (odd) lands in bufA
    for (int t = 0; t < kT; ++t) {
        const float* hp = (t & 1) ? bufB : bufA;
        float* ho       = (t & 1) ? bufA : bufB;
        gru_step<<<256, 192, 0, stream>>>(
            gx1 + (size_t)t * 3 * kH, gx_bstride,
            w_hh_l1, b_hh_l1,
            hp, (long)kH, (t == 0) ? 1 : 0,
            ho, (long)kH);
    }

    // Decoder: out = h2_last @ dec_w^T + dec_b   (M=16, N=4096, K=1024)
    gemm_nt_bias<<<dim3(4096 / GBN, 1), 256, 0, stream>>>(
        bufA, dec_w, dec_b, out, kB, 4096, 1024);
}